// Round 10
// baseline (168.377 us; speedup 1.0000x reference)
//
#include <hip/hip_runtime.h>
#include <math.h>

// Problem constants (match reference)
#define BATCH 1024
#define NV    64      // N_VARS
#define MC    256     // M_CLAUSES
#define KD    12      // K_DIM
#define PI_F  3.14159265358979323846f

// ws/LDS layout (floats):
//   rows: q*68 + (j-1), j=1..64 = C[v][j], v = q+1 (FULL row, natural order)
//   c0N[64]  at C0OFF: C[v][0]        (init only)
//   diag[64] at DIOFF: C[v][v]
//   dga[64]  at DGOFF: C[v][prev1(v)] (prev1(1)=64)
#define CBUF  4544
#define C0OFF 4352
#define DIOFF 4416
#define DGOFF 4480

// ---- DPP add helpers (bound_ctrl=true). 0xB1 qp xor1, 0x4E qp xor2,
// 0x124 row_ror:4, 0x128 row_ror:8, 0x142 row_bcast15, 0x143 row_bcast31.
template <int CTRL>
__device__ __forceinline__ float dpp_addf(float x) {
  int y = __builtin_amdgcn_update_dpp(0, __float_as_int(x), CTRL, 0xF, 0xF, true);
  return x + __int_as_float(y);
}
__device__ __forceinline__ float allreduce16(float x) {
  x = dpp_addf<0xB1>(x);
  x = dpp_addf<0x4E>(x);
  x = dpp_addf<0x124>(x);
  x = dpp_addf<0x128>(x);
  return x;
}
__device__ __forceinline__ float readlane63(float x) {
  return __int_as_float(__builtin_amdgcn_readlane(__float_as_int(x), 63));
}
__device__ __forceinline__ float bperm(int byteidx, float x) {
  return __int_as_float(__builtin_amdgcn_ds_bpermute(byteidx, __float_as_int(x)));
}

// ---- Kernel 1: full Gram rows (natural order) + c0/diag/dga tables ---------
__global__ void compute_C_kernel(const float* __restrict__ S,
                                 const float* __restrict__ w,
                                 float* __restrict__ Cg, int nsplit) {
  const int q = blockIdx.x;   // var v = q+1
  const int mc = blockIdx.y;
  const int j = threadIdx.x;  // column 0..64
  if (j > NV) return;
  const int v = q + 1;
  const int mlen = MC / nsplit;
  const int m0 = mc * mlen;
  float a0 = 0.f, a1 = 0.f, a2 = 0.f, a3 = 0.f;
  for (int m = m0; m < m0 + mlen; m += 4) {
    const float w0 = w[m], w1 = w[m + 1], w2 = w[m + 2], w3 = w[m + 3];
    a0 = fmaf(S[(m + 0) * (NV + 1) + v] * w0 * w0, S[(m + 0) * (NV + 1) + j], a0);
    a1 = fmaf(S[(m + 1) * (NV + 1) + v] * w1 * w1, S[(m + 1) * (NV + 1) + j], a1);
    a2 = fmaf(S[(m + 2) * (NV + 1) + v] * w2 * w2, S[(m + 2) * (NV + 1) + j], a2);
    a3 = fmaf(S[(m + 3) * (NV + 1) + v] * w3 * w3, S[(m + 3) * (NV + 1) + j], a3);
  }
  const float acc = (a0 + a1) + (a2 + a3);
  float* buf = Cg + mc * CBUF;
  const int p1 = (v == 1) ? 64 : (v - 1);
  if (j == 0) buf[C0OFF + q] = acc;
  if (j == v) buf[DIOFF + q] = acc;
  if (j == p1) buf[DGOFF + q] = acc;
  if (j > 0) buf[q * 68 + (j - 1)] = acc;  // full row, no zeroing
}

// ---- Kernel 2: incremental-G mixing (no per-step butterfly) ----------------
// Block = 256 thr = 4 waves = 4 batches, shared LDS C. Wave: kq = l>>4 owns
// k-triple {3kq..3kq+2}; n16 = l&15 owns vars 4*n16+1..4*n16+4.
// State per lane: V[4][3] and G[4][3] where G[n] = sum_m C[n,m] V[m]
// (distributed by owner; incremental, mirrors reference's W-update).
// Step i (owner ii, slot s):
//   (issued one step early) gg' = G[i] - C[i,i] V[i] on owner; 3+3 ds_bpermute
//     broadcast gg' and V[i] to the wave (latency hidden by one full step).
//   gg = bp + dga_i * Delta_{i-1}   (repairs the one-step staleness)
//   n2 = |gg|^2 -> 2 dpp bcast -> readlane63 -> rsq; vn = -gg*inv (replicated)
//   Delta = vn - vo (exactly replicated); owner writes V[s].
//   G[s'] += crow_i[s'] * Delta  (12 fma, full row incl. diagonal).
__global__ __launch_bounds__(256, 1) void mixing_kernel(
    const float* __restrict__ z, const float* __restrict__ r,
    const float* __restrict__ Cg, const int* __restrict__ max_iter_p,
    float* __restrict__ out, int nsplit) {
  __shared__ float Ls[CBUF];  // 18176 B

  const int t = threadIdx.x;
  const int l = t & 63;
  const int kq = l >> 4;
  const int n16 = l & 15;
  const int b = blockIdx.x * 4 + (t >> 6);
  const int max_iter = max_iter_p[0];

  // stage (and m-split-reduce) C into LDS
  {
    const float4* src = (const float4*)Cg;
    float4* dst = (float4*)Ls;
    for (int idx = t; idx < CBUF / 4; idx += 256) {
      float4 a = src[idx];
      for (int u = 1; u < nsplit; ++u) {
        const float4 p = src[u * (CBUF / 4) + idx];
        a.x += p.x; a.y += p.y; a.z += p.z; a.w += p.w;
      }
      dst[idx] = a;
    }
  }

  const float row0 = (kq == 0) ? 1.f : 0.f;

  // ---- init: V[n] = -cos(pi z) e0 + sin(pi z) * r_perp_hat ----
  float V[4][3];
  #pragma unroll
  for (int s = 0; s < 4; ++s) {
    const int n = 4 * n16 + s;
    const float zv = z[b * NV + n];
    float rp[3];
    float ssp = 0.f;
    #pragma unroll
    for (int j = 0; j < 3; ++j) {
      const int k = 3 * kq + j;
      rp[j] = (k == 0) ? 0.f : r[(b * NV + n) * KD + k];
      ssp = fmaf(rp[j], rp[j], ssp);
    }
    ssp += __shfl_xor(ssp, 16, 64);
    ssp += __shfl_xor(ssp, 32, 64);
    const float inv = 1.f / fmaxf(sqrtf(ssp), 1e-8f);
    float sn, cs;
    sincosf(PI_F * zv, &sn, &cs);
    #pragma unroll
    for (int j = 0; j < 3; ++j) {
      const int k = 3 * kq + j;
      V[s][j] = (k == 0) ? -cs : sn * rp[j] * inv;
    }
  }

  __syncthreads();

  const float4* C4  = (const float4*)Ls;             // [q*17 + n16]
  const float4* Di4 = (const float4*)(Ls + DIOFF);   // [g]
  const float4* Dg4 = (const float4*)(Ls + DGOFF);   // [g]

  // ---- init G[n] = sum_m C[n,m] V[m] (+ c0 on k=0): one-time butterfly ----
  float G[4][3] = {{0.f,0.f,0.f},{0.f,0.f,0.f},{0.f,0.f,0.f},{0.f,0.f,0.f}};
  for (int q16 = 0; q16 < 16; ++q16) {
    const bool ow = (n16 == q16);
    #pragma unroll
    for (int s = 0; s < 4; ++s) {
      const int q = 4 * q16 + s;
      const float4 ce = C4[q * 17 + n16];
      float q0 = ce.x * V[0][0];
      float q1 = ce.x * V[0][1];
      float q2 = ce.x * V[0][2];
      q0 = fmaf(ce.y, V[1][0], q0); q1 = fmaf(ce.y, V[1][1], q1); q2 = fmaf(ce.y, V[1][2], q2);
      q0 = fmaf(ce.z, V[2][0], q0); q1 = fmaf(ce.z, V[2][1], q1); q2 = fmaf(ce.z, V[2][2], q2);
      q0 = fmaf(ce.w, V[3][0], q0); q1 = fmaf(ce.w, V[3][1], q1); q2 = fmaf(ce.w, V[3][2], q2);
      q0 = allreduce16(q0);
      q1 = allreduce16(q1);
      q2 = allreduce16(q2);
      q0 = fmaf(row0, Ls[C0OFF + q], q0);
      G[s][0] = ow ? q0 : G[s][0];
      G[s][1] = ow ? q1 : G[s][1];
      G[s][2] = ow ? q2 : G[s][2];
    }
  }

  const int bpbase = (l & 48) << 2;  // byte index of this row's lane 0

  float4 cbA[4], cbB[4], diA, diB, dgA, dgB;
  auto prefetch = [&](float4 cb[4], float4& dib, float4& dgb, int g) {
    #pragma unroll
    for (int s = 0; s < 4; ++s) cb[s] = C4[(4 * g + s) * 17 + n16];
    dib = Di4[g];
    dgb = Dg4[g];
  };

  float bp[3], vo[3], d[3];

  prefetch(cbA, diA, dgA, 0);

  // ---- prologue: broadcast gg'_1 and v_old_1 (owner lane 0); Delta_0 = 0 ---
  {
    float gp0 = fmaf(-diA.x, V[0][0], G[0][0]);
    float gp1 = fmaf(-diA.x, V[0][1], G[0][1]);
    float gp2 = fmaf(-diA.x, V[0][2], G[0][2]);
    bp[0] = bperm(bpbase, gp0);
    bp[1] = bperm(bpbase, gp1);
    bp[2] = bperm(bpbase, gp2);
    vo[0] = bperm(bpbase, V[0][0]);
    vo[1] = bperm(bpbase, V[0][1]);
    vo[2] = bperm(bpbase, V[0][2]);
    d[0] = 0.f; d[1] = 0.f; d[2] = 0.f;
  }

  auto do_group = [&](int ii, const float4 cb[4], const float4& dib,
                      const float4& dgb, float diNextX) {
    const bool own = (n16 == ii);
    const float* dip = &dib.x;
    const float* dgp = &dgb.x;
    const int idxC = bpbase + 4 * ii;                 // source lane for s<3
    const int idxN = bpbase + ((4 * ii + 4) & 63);    // source for s==3 wrap
    #pragma unroll
    for (int s = 0; s < 4; ++s) {
      const int snext = (s + 1) & 3;
      const float diag_n = (s < 3) ? dip[s + 1] : diNextX;
      const int idx = (s < 3) ? idxC : idxN;

      // ---- broadcast for NEXT step (latency hidden by this whole step) ----
      const float gp0 = fmaf(-diag_n, V[snext][0], G[snext][0]);
      const float gp1 = fmaf(-diag_n, V[snext][1], G[snext][1]);
      const float gp2 = fmaf(-diag_n, V[snext][2], G[snext][2]);
      const float bpn0 = bperm(idx, gp0);
      const float bpn1 = bperm(idx, gp1);
      const float bpn2 = bperm(idx, gp2);
      const float von0 = bperm(idx, V[snext][0]);
      const float von1 = bperm(idx, V[snext][1]);
      const float von2 = bperm(idx, V[snext][2]);

      // ---- finish current step: staleness repair + norm chain ----
      const float gg0 = fmaf(dgp[s], d[0], bp[0]);
      const float gg1 = fmaf(dgp[s], d[1], bp[1]);
      const float gg2 = fmaf(dgp[s], d[2], bp[2]);
      float n2p = gg0 * gg0;
      n2p = fmaf(gg1, gg1, n2p);
      n2p = fmaf(gg2, gg2, n2p);
      n2p = dpp_addf<0x142>(n2p);
      n2p = dpp_addf<0x143>(n2p);
      const float n2 = readlane63(n2p);
      const float inv = __builtin_amdgcn_rsqf(fmaxf(n2, 1e-16f));
      const float vn0 = -gg0 * inv, vn1 = -gg1 * inv, vn2 = -gg2 * inv;
      const float dn0 = vn0 - vo[0], dn1 = vn1 - vo[1], dn2 = vn2 - vo[2];

      V[s][0] = own ? vn0 : V[s][0];
      V[s][1] = own ? vn1 : V[s][1];
      V[s][2] = own ? vn2 : V[s][2];

      // ---- G update: full row i (incl. diagonal), Delta replicated ----
      const float4 ce = cb[s];
      G[0][0] = fmaf(ce.x, dn0, G[0][0]); G[0][1] = fmaf(ce.x, dn1, G[0][1]); G[0][2] = fmaf(ce.x, dn2, G[0][2]);
      G[1][0] = fmaf(ce.y, dn0, G[1][0]); G[1][1] = fmaf(ce.y, dn1, G[1][1]); G[1][2] = fmaf(ce.y, dn2, G[1][2]);
      G[2][0] = fmaf(ce.z, dn0, G[2][0]); G[2][1] = fmaf(ce.z, dn1, G[2][1]); G[2][2] = fmaf(ce.z, dn2, G[2][2]);
      G[3][0] = fmaf(ce.w, dn0, G[3][0]); G[3][1] = fmaf(ce.w, dn1, G[3][1]); G[3][2] = fmaf(ce.w, dn2, G[3][2]);

      // rotate carried state (renamed by unroll)
      bp[0] = bpn0; bp[1] = bpn1; bp[2] = bpn2;
      vo[0] = von0; vo[1] = von1; vo[2] = von2;
      d[0] = dn0;   d[1] = dn1;   d[2] = dn2;
    }
  };

  // ---- sweeps ----
  for (int it = 0; it < max_iter; ++it) {
    for (int ih = 0; ih < 8; ++ih) {
      prefetch(cbB, diB, dgB, 2 * ih + 1);
      do_group(2 * ih, cbA, diA, dgA, diB.x);
      prefetch(cbA, diA, dgA, (2 * ih + 2) & 15);
      do_group(2 * ih + 1, cbB, diB, dgB, diA.x);
    }
  }

  // ---- epilogue: kq==0 lanes hold k=0 ----
  if (kq == 0) {
    float4 o;
    float* op = &o.x;
    #pragma unroll
    for (int s = 0; s < 4; ++s) {
      float cv = -V[s][0];
      cv = fminf(fmaxf(cv, -1.f + 1e-6f), 1.f - 1e-6f);
      op[s] = acosf(cv) * (1.f / PI_F);
    }
    ((float4*)(out + b * NV))[n16] = o;
  }
}

extern "C" void kernel_launch(void* const* d_in, const int* in_sizes, int n_in,
                              void* d_out, int out_size, void* d_ws, size_t ws_size,
                              hipStream_t stream) {
  const float* z = (const float*)d_in[0];
  const float* S = (const float*)d_in[1];
  const float* w = (const float*)d_in[2];
  const float* r = (const float*)d_in[3];
  const int* max_iter = (const int*)d_in[4];
  float* Cg = (float*)d_ws;

  const int nsplit = (ws_size >= (size_t)8 * CBUF * 4) ? 8
                   : (ws_size >= (size_t)4 * CBUF * 4) ? 4 : 1;
  compute_C_kernel<<<dim3(NV, nsplit), 128, 0, stream>>>(S, w, Cg, nsplit);
  mixing_kernel<<<BATCH / 4, 256, 0, stream>>>(z, r, Cg, max_iter,
                                               (float*)d_out, nsplit);
}

// Round 12
// 147.779 us; speedup vs baseline: 1.1394x; 1.1394x over previous
//
#include <hip/hip_runtime.h>
#include <math.h>

// Problem constants (match reference)
#define BATCH 1024
#define NV    64      // N_VARS
#define MC    256     // M_CLAUSES
#define KD    12      // K_DIM
#define PI_F  3.14159265358979323846f

// ws/LDS layout (floats):
//   NR rows 64x68: row q = C-row of var v = nv(q) = (q+1)%64+1, slot j =
//     C[v][j+1], with cols {v-2, v-1, v} (wrapped in 1..64) PRE-ZEROED.
//   c0N[64]  at C0OFF : C[v][0]
//   DgA[64]  at DGAOFF: DgA[v-1] = C[v][prev1(v)]  (prev1(1)=64)
//   DgB[64]  at DGBOFF: DgB[v-1] = C[v][prev2(v)]  (prev2(1)=63, prev2(2)=64)
#define CBUF   4544
#define C0OFF  4352
#define DGAOFF 4416
#define DGBOFF 4480

typedef float f2 __attribute__((ext_vector_type(2)));

// ---- DPP add helpers (intrinsic form: bound_ctrl=true, old=0 -> the
// canonical GCNDPPCombine-fusable pattern; compiler inserts required DPP
// hazard wait-states). 0xB1 qp xor1, 0x4E qp xor2, 0x124 row_ror:4,
// 0x128 row_ror:8, 0x142 row_bcast15, 0x143 row_bcast31.
template <int CTRL>
__device__ __forceinline__ float dpp_addf(float x) {
  int y = __builtin_amdgcn_update_dpp(0, __float_as_int(x), CTRL, 0xF, 0xF, true);
  return x + __int_as_float(y);
}
__device__ __forceinline__ float allreduce16(float x) {
  x = dpp_addf<0xB1>(x);
  x = dpp_addf<0x4E>(x);
  x = dpp_addf<0x124>(x);
  x = dpp_addf<0x128>(x);
  return x;
}
__device__ __forceinline__ float readlane63(float x) {
  return __int_as_float(__builtin_amdgcn_readlane(__float_as_int(x), 63));
}

// ---- Kernel 1: Gram rows (pre-zeroed excl. columns) + c0/dgA/dgB tables ----
__global__ void compute_C_kernel(const float* __restrict__ S,
                                 const float* __restrict__ w,
                                 float* __restrict__ Cg, int nsplit) {
  const int q = blockIdx.x;
  const int mc = blockIdx.y;
  const int j = threadIdx.x;  // column 0..64
  if (j > NV) return;
  const int v = (q + 1) % 64 + 1;
  const int mlen = MC / nsplit;
  const int m0 = mc * mlen;
  float a0 = 0.f, a1 = 0.f, a2 = 0.f, a3 = 0.f;
  for (int m = m0; m < m0 + mlen; m += 4) {
    const float w0 = w[m], w1 = w[m + 1], w2 = w[m + 2], w3 = w[m + 3];
    a0 = fmaf(S[(m + 0) * (NV + 1) + v] * w0 * w0, S[(m + 0) * (NV + 1) + j], a0);
    a1 = fmaf(S[(m + 1) * (NV + 1) + v] * w1 * w1, S[(m + 1) * (NV + 1) + j], a1);
    a2 = fmaf(S[(m + 2) * (NV + 1) + v] * w2 * w2, S[(m + 2) * (NV + 1) + j], a2);
    a3 = fmaf(S[(m + 3) * (NV + 1) + v] * w3 * w3, S[(m + 3) * (NV + 1) + j], a3);
  }
  const float acc = (a0 + a1) + (a2 + a3);
  float* buf = Cg + mc * CBUF;
  const int p1 = (v == 1) ? 64 : (v - 1);
  const int p2 = (v == 1) ? 63 : (v == 2) ? 64 : (v - 2);
  if (j == 0) buf[C0OFF + q] = acc;
  if (j == p1) buf[DGAOFF + (v - 1)] = acc;
  if (j == p2) buf[DGBOFF + (v - 1)] = acc;
  if (j > 0) {
    // pre-zero the columns Phase B must exclude: {v-2, v-1, v}
    const float st = (j == v || j == p1 || j == p2) ? 0.f : acc;
    buf[q * 68 + (j - 1)] = st;
  }
}

// ---- Kernel 2: two-column-deferred mixing, packed-fp32 k-pairs -------------
// Block = 256 thr = 4 waves = 4 batches, shared LDS C. Wave: kq = l>>4 owns
// k-triple {3kq..3kq+2}; n16 = l&15 owns vars 4*n16+1..4*n16+4.
// Per lane: V01[4] (f2: k0,k1) + V2[4] (k2). Carried: P01/P2 = Q_i (dot
// missing cols i-1,i-2), vp1*/vp2* = u_{i-1}/u_{i-2}.
// Step i: B) Q_{i+1} from pre-zeroed row via v_pk_fma_f32 (8 slots vs 12);
// A) g = P + DgA*vp1 + DgB*vp2 (pk) -> norm chain -> v_new; C) delayed
// writeback of u_{i-1}. DPP hops act on the pair's subregisters in place.
__global__ __launch_bounds__(256, 1) void mixing_kernel(
    const float* __restrict__ z, const float* __restrict__ r,
    const float* __restrict__ Cg, const int* __restrict__ max_iter_p,
    float* __restrict__ out, int nsplit) {
  __shared__ float Ls[CBUF];  // 18176 B

  const int t = threadIdx.x;
  const int l = t & 63;
  const int kq = l >> 4;
  const int n16 = l & 15;
  const int b = blockIdx.x * 4 + (t >> 6);
  const int max_iter = max_iter_p[0];

  // stage (and m-split-reduce) C into LDS
  {
    const float4* src = (const float4*)Cg;
    float4* dst = (float4*)Ls;
    for (int idx = t; idx < CBUF / 4; idx += 256) {
      float4 a = src[idx];
      for (int u = 1; u < nsplit; ++u) {
        const float4 p = src[u * (CBUF / 4) + idx];
        a.x += p.x; a.y += p.y; a.z += p.z; a.w += p.w;
      }
      dst[idx] = a;
    }
  }

  const float row0 = (kq == 0) ? 1.f : 0.f;

  // ---- init: V[n] = -cos(pi z) e0 + sin(pi z) * r_perp_hat ----
  f2 V01[4];
  float V2[4];
  #pragma unroll
  for (int s = 0; s < 4; ++s) {
    const int n = 4 * n16 + s;
    const float zv = z[b * NV + n];
    float rp[3];
    float ssp = 0.f;
    #pragma unroll
    for (int j = 0; j < 3; ++j) {
      const int k = 3 * kq + j;
      rp[j] = (k == 0) ? 0.f : r[(b * NV + n) * KD + k];
      ssp = fmaf(rp[j], rp[j], ssp);
    }
    ssp += __shfl_xor(ssp, 16, 64);
    ssp += __shfl_xor(ssp, 32, 64);
    const float inv = 1.f / fmaxf(sqrtf(ssp), 1e-8f);
    float sn, cs;
    sincosf(PI_F * zv, &sn, &cs);
    float vv[3];
    #pragma unroll
    for (int j = 0; j < 3; ++j) {
      const int k = 3 * kq + j;
      vv[j] = (k == 0) ? -cs : sn * rp[j] * inv;
    }
    V01[s].x = vv[0];
    V01[s].y = vv[1];
    V2[s] = vv[2];
  }

  __syncthreads();

  const float4* C4   = (const float4*)Ls;               // [q*17 + n16]
  const float4* C04  = (const float4*)(Ls + C0OFF);     // [g]
  const float4* DgA4 = (const float4*)(Ls + DGAOFF);    // [g]
  const float4* DgB4 = (const float4*)(Ls + DGBOFF);    // [g]

  f2 P01, vp1_01, vp2_01;
  float P2, vp1_2, vp2_2;

  // ---- prologue: Q_1 from pre-zeroed row NR[63] (= C[1]);
  //      vp1 = V_init[var64] (slot63), vp2 = V_init[var63] (slot62) ----
  {
    const float4 ce = C4[63 * 17 + n16];
    const float c0 = Ls[C0OFF + 63];
    f2 q01 = ce.x * V01[0];
    float q2 = ce.x * V2[0];
    q01 = __builtin_elementwise_fma((f2){ce.y, ce.y}, V01[1], q01);
    q2 = fmaf(ce.y, V2[1], q2);
    q01 = __builtin_elementwise_fma((f2){ce.z, ce.z}, V01[2], q01);
    q2 = fmaf(ce.z, V2[2], q2);
    q01 = __builtin_elementwise_fma((f2){ce.w, ce.w}, V01[3], q01);
    q2 = fmaf(ce.w, V2[3], q2);
    q01.x = allreduce16(q01.x);
    q01.y = allreduce16(q01.y);
    q2 = allreduce16(q2);
    q01.x = fmaf(row0, c0, q01.x);
    P01 = q01; P2 = q2;
    const int src = l | 15;  // this row's lane 15
    vp1_01.x = __shfl(V01[3].x, src, 64);
    vp1_01.y = __shfl(V01[3].y, src, 64);
    vp1_2    = __shfl(V2[3],    src, 64);
    vp2_01.x = __shfl(V01[2].x, src, 64);
    vp2_01.y = __shfl(V01[2].y, src, 64);
    vp2_2    = __shfl(V2[2],    src, 64);
  }

  float4 cbA[4], cbB[4], c0A, c0B, daA, daB, dbA, dbB;

  auto prefetch = [&](float4 cb[4], float4& c0b, float4& dab, float4& dbb, int g) {
    #pragma unroll
    for (int s = 0; s < 4; ++s) cb[s] = C4[(4 * g + s) * 17 + n16];
    c0b = C04[g];
    dab = DgA4[g];
    dbb = DgB4[g];
  };

  auto do_group = [&](int ii, const float4 cb[4], const float4& c0b,
                      const float4& dab, const float4& dbb) {
    const bool own  = (n16 == ii);
    const bool ownP = (n16 == ((ii + 15) & 15));
    const float* c0p = &c0b.x;
    const float* dap = &dab.x;
    const float* dbp = &dbb.x;
    #pragma unroll
    for (int s = 0; s < 4; ++s) {
      const float4 ce = cb[s];
      const float db = dbp[s], da = dap[s];

      // ---- Phase A start: the true recurrence (g, n2 partial) ----
      f2 g01 = __builtin_elementwise_fma((f2){db, db}, vp2_01, P01);
      float g2 = fmaf(db, vp2_2, P2);
      g01 = __builtin_elementwise_fma((f2){da, da}, vp1_01, g01);
      g2 = fmaf(da, vp1_2, g2);

      // ---- Phase B products (independent; packed k0k1 + scalar k2) ----
      f2 q01 = ce.x * V01[0];
      float q2 = ce.x * V2[0];
      q01 = __builtin_elementwise_fma((f2){ce.y, ce.y}, V01[1], q01);
      q2 = fmaf(ce.y, V2[1], q2);
      q01 = __builtin_elementwise_fma((f2){ce.z, ce.z}, V01[2], q01);
      q2 = fmaf(ce.z, V2[2], q2);
      q01 = __builtin_elementwise_fma((f2){ce.w, ce.w}, V01[3], q01);
      q2 = fmaf(ce.w, V2[3], q2);

      float n2p = g01.x * g01.x;
      n2p = fmaf(g01.y, g01.y, n2p);
      n2p = fmaf(g2, g2, n2p);

      // ---- cross-lane: A's bcast chain + B's butterflies, hop-major ----
      n2p = dpp_addf<0x142>(n2p);                 // A: row1+=row0, row3+=row2
      q01.x = dpp_addf<0xB1>(q01.x);              // B hop 1
      q01.y = dpp_addf<0xB1>(q01.y);
      q2 = dpp_addf<0xB1>(q2);
      n2p = dpp_addf<0x143>(n2p);                 // A: lane63 = total
      q01.x = dpp_addf<0x4E>(q01.x);              // B hop 2
      q01.y = dpp_addf<0x4E>(q01.y);
      q2 = dpp_addf<0x4E>(q2);
      const float n2 = readlane63(n2p);           // A tail starts
      q01.x = dpp_addf<0x124>(q01.x);             // B hop 3
      q01.y = dpp_addf<0x124>(q01.y);
      q2 = dpp_addf<0x124>(q2);
      const float inv = __builtin_amdgcn_rsqf(fmaxf(n2, 1e-16f));
      q01.x = dpp_addf<0x128>(q01.x);             // B hop 4
      q01.y = dpp_addf<0x128>(q01.y);
      q2 = dpp_addf<0x128>(q2);
      const f2 vn01 = g01 * (f2){-inv, -inv};     // == -g * inv (exact)
      const float vn2 = -g2 * inv;
      q01.x = fmaf(row0, c0p[s], q01.x);          // e0 term -> k=0 only

      // ---- Phase C: delayed writeback of u_{i-1} (held in vp1) ----
      if (s == 0) {
        V01[3].x = ownP ? vp1_01.x : V01[3].x;
        V01[3].y = ownP ? vp1_01.y : V01[3].y;
        V2[3]    = ownP ? vp1_2    : V2[3];
      } else {
        V01[s - 1].x = own ? vp1_01.x : V01[s - 1].x;
        V01[s - 1].y = own ? vp1_01.y : V01[s - 1].y;
        V2[s - 1]    = own ? vp1_2    : V2[s - 1];
      }

      // rotate carried state (renamed by unroll)
      vp2_01 = vp1_01; vp2_2 = vp1_2;
      vp1_01 = vn01;   vp1_2 = vn2;
      P01 = q01;       P2 = q2;
    }
  };

  prefetch(cbA, c0A, daA, dbA, 0);

  // ---- sweeps (groups of 4 steps; ping-pong prefetch, unroll by 2) ----
  for (int it = 0; it < max_iter; ++it) {
    for (int ih = 0; ih < 8; ++ih) {
      prefetch(cbB, c0B, daB, dbB, 2 * ih + 1);
      do_group(2 * ih, cbA, c0A, daA, dbA);
      prefetch(cbA, c0A, daA, dbA, (2 * ih + 2) & 15);
      do_group(2 * ih + 1, cbB, c0B, daB, dbB);
    }
  }

  // final pending writeback: u_64 still in vp1 -> slot 63 (lane 15, V[3])
  {
    const bool l15 = (n16 == 15);
    V01[3].x = l15 ? vp1_01.x : V01[3].x;
    V01[3].y = l15 ? vp1_01.y : V01[3].y;
    V2[3]    = l15 ? vp1_2    : V2[3];
  }

  // ---- epilogue: kq==0 lanes hold k=0 ----
  if (kq == 0) {
    float4 o;
    float* op = &o.x;
    #pragma unroll
    for (int s = 0; s < 4; ++s) {
      float cv = -V01[s].x;
      cv = fminf(fmaxf(cv, -1.f + 1e-6f), 1.f - 1e-6f);
      op[s] = acosf(cv) * (1.f / PI_F);
    }
    ((float4*)(out + b * NV))[n16] = o;
  }
}

extern "C" void kernel_launch(void* const* d_in, const int* in_sizes, int n_in,
                              void* d_out, int out_size, void* d_ws, size_t ws_size,
                              hipStream_t stream) {
  const float* z = (const float*)d_in[0];
  const float* S = (const float*)d_in[1];
  const float* w = (const float*)d_in[2];
  const float* r = (const float*)d_in[3];
  const int* max_iter = (const int*)d_in[4];
  float* Cg = (float*)d_ws;

  const int nsplit = (ws_size >= (size_t)8 * CBUF * 4) ? 8
                   : (ws_size >= (size_t)4 * CBUF * 4) ? 4 : 1;
  compute_C_kernel<<<dim3(NV, nsplit), 128, 0, stream>>>(S, w, Cg, nsplit);
  mixing_kernel<<<BATCH / 4, 256, 0, stream>>>(z, r, Cg, max_iter,
                                               (float*)d_out, nsplit);
}